// Round 4
// baseline (395.814 us; speedup 1.0000x reference)
//
#include <hip/hip_runtime.h>
#include <hip/hip_bf16.h>
#include <math.h>

typedef __bf16 bf16;
typedef __bf16 bf16x4 __attribute__((ext_vector_type(4)));
typedef __bf16 bf16x8 __attribute__((ext_vector_type(8)));
typedef float  f32x4  __attribute__((ext_vector_type(4)));

#define T_SEQ 2048
#define E_DIM 1024
#define H_NUM 16
#define D_DIM 64
#define NDELTA 4095   // 2*T_SEQ-1

// ---------------- fp32 -> bf16 cast (vectorized) ----------------
__global__ void cast_bf16_kernel(const float* __restrict__ src, bf16* __restrict__ dst, int n4) {
  int i = blockIdx.x * blockDim.x + threadIdx.x;
  if (i >= n4) return;
  const float4 v = reinterpret_cast<const float4*>(src)[i];
  bf16x4 o;
  o[0] = (bf16)v.x; o[1] = (bf16)v.y; o[2] = (bf16)v.z; o[3] = (bf16)v.w;
  reinterpret_cast<bf16x4*>(dst)[i] = o;
}

// ---------------- relative-position-bias table: pbt[h][delta+2047] ----------------
__global__ void pb_kernel(const float* __restrict__ rel_embed, float* __restrict__ pbt) {
  int dd = blockIdx.x * 64 + threadIdx.x;   // 0..4094
  if (dd >= NDELTA) return;
  int delta = dd - (T_SEQ - 1);
  int bucket = (delta > 0) ? 160 : 0;       // NUM_BUCKETS/2
  int rel = abs(delta);
  int v;
  if (rel < 80) {                            // max_exact
    v = rel;
  } else {
    float rf = (float)(rel < 1 ? 1 : rel);
    float lf = logf(rf / 80.0f) * (80.0f / 2.302585092994046f); // log(800/80)=log(10)
    int lg = 80 + (int)lf;
    v = lg < 159 ? lg : 159;
  }
  bucket += v;
#pragma unroll
  for (int h = 0; h < H_NUM; h++)
    pbt[h * NDELTA + dd] = rel_embed[bucket * H_NUM + h];
}

// ---------------- gate: g[b][h][t] = ga*(gb*const[h]-1)+2 ----------------
__global__ __launch_bounds__(256)
void gate_kernel(const float* __restrict__ hs, const float* __restrict__ gru_w,
                 const float* __restrict__ gru_b, const float* __restrict__ gconst,
                 float* __restrict__ gate)
{
  __shared__ float w[512];
  int tid = threadIdx.x;
  w[tid] = gru_w[tid];
  w[tid + 256] = gru_w[tid + 256];
  __syncthreads();
  int idx = blockIdx.x * 256 + tid;  // (b*T+t)*16 + h, 65536 total
  int h  = idx & 15;
  int bt = idx >> 4;
  const float* x = hs + (size_t)bt * E_DIM + h * D_DIM;
  float acc[8] = {0,0,0,0,0,0,0,0};
  for (int d = 0; d < 64; d += 4) {
    float4 xv = *(const float4*)&x[d];
#pragma unroll
    for (int e = 0; e < 8; e++) {
      acc[e] += xv.x * w[e*64+d] + xv.y * w[e*64+d+1]
              + xv.z * w[e*64+d+2] + xv.w * w[e*64+d+3];
    }
  }
  float p0 = acc[0]+acc[1]+acc[2]+acc[3] + gru_b[0]+gru_b[1]+gru_b[2]+gru_b[3];
  float p1 = acc[4]+acc[5]+acc[6]+acc[7] + gru_b[4]+gru_b[5]+gru_b[6]+gru_b[7];
  float ga = 1.0f / (1.0f + expf(-p0));
  float gb = 1.0f / (1.0f + expf(-p1));
  float g = ga * (gb * gconst[h] - 1.0f) + 2.0f;
  int bb = bt >> 11;
  int t  = bt & (T_SEQ - 1);
  gate[((size_t)(bb * H_NUM + h)) * T_SEQ + t] = g;
}

// ---------------- GEMM: C[m][n] = (sum_k A[m][k]*W[n][k] + bias[n]) * alpha ----------------
// BM=BN=128, BK=32; 256 threads = 4 waves, each wave 64x64 via 4x4 MFMA 16x16x32 tiles.
#define LDA 40   // padded LDS row stride (bf16 elems)
template<bool OUT_BF16>
__global__ __launch_bounds__(256)
void gemm_bt_kernel(const bf16* __restrict__ A, const bf16* __restrict__ W,
                    const float* __restrict__ bias, float alpha,
                    void* __restrict__ Cout, int M, int N, int K)
{
  __shared__ bf16 As[128 * LDA];
  __shared__ bf16 Bs[128 * LDA];
  const int tid  = threadIdx.x;
  const int lane = tid & 63;
  const int wave = tid >> 6;
  const int m0 = blockIdx.y * 128;
  const int n0 = blockIdx.x * 128;
  const int wm = (wave >> 1) * 64;
  const int wn = (wave & 1) * 64;
  const int qd = lane >> 4;
  const int lm = lane & 15;
  const int srow = tid >> 2;        // 0..63
  const int sk   = (tid & 3) * 8;   // k chunk (8 bf16 = 16B)

  f32x4 acc[4][4] = {};

  for (int k0 = 0; k0 < K; k0 += 32) {
    const bf16* ga = A + (size_t)(m0 + srow) * K + (k0 + sk);
    const bf16* gw = W + (size_t)(n0 + srow) * K + (k0 + sk);
    bf16x8 a0 = *(const bf16x8*)ga;
    bf16x8 a1 = *(const bf16x8*)(ga + (size_t)64 * K);
    bf16x8 b0 = *(const bf16x8*)gw;
    bf16x8 b1 = *(const bf16x8*)(gw + (size_t)64 * K);
    *(bf16x8*)&As[srow * LDA + sk]        = a0;
    *(bf16x8*)&As[(64 + srow) * LDA + sk] = a1;
    *(bf16x8*)&Bs[srow * LDA + sk]        = b0;
    *(bf16x8*)&Bs[(64 + srow) * LDA + sk] = b1;
    __syncthreads();
    bf16x8 af[4], bfr[4];
#pragma unroll
    for (int i = 0; i < 4; i++) {
      af[i]  = *(const bf16x8*)&As[(wm + i * 16 + lm) * LDA + qd * 8];
      bfr[i] = *(const bf16x8*)&Bs[(wn + i * 16 + lm) * LDA + qd * 8];
    }
#pragma unroll
    for (int im = 0; im < 4; im++)
#pragma unroll
      for (int in = 0; in < 4; in++)
        acc[im][in] = __builtin_amdgcn_mfma_f32_16x16x32_bf16(af[im], bfr[in], acc[im][in], 0, 0, 0);
    __syncthreads();
  }

#pragma unroll
  for (int im = 0; im < 4; im++) {
#pragma unroll
    for (int in = 0; in < 4; in++) {
      int n = n0 + wn + in * 16 + lm;
      float bv = bias[n];
#pragma unroll
      for (int r = 0; r < 4; r++) {
        int m = m0 + wm + im * 16 + qd * 4 + r;
        float v = (acc[im][in][r] + bv) * alpha;
        if (OUT_BF16) ((bf16*)Cout)[(size_t)m * N + n] = (bf16)v;
        else          ((float*)Cout)[(size_t)m * N + n] = v;
      }
    }
  }
}

// ---------------- flash attention with gated relative bias ----------------
// block = (q-tile of 64 rows, head, batch); 4 waves, wave owns 16 q-rows.
#define LQ 72    // padded LDS row stride
__global__ __launch_bounds__(256)
void attn_kernel(const bf16* __restrict__ Qb, const bf16* __restrict__ Kb,
                 const bf16* __restrict__ Vb, const float* __restrict__ gate,
                 const float* __restrict__ pbt, bf16* __restrict__ ctx)
{
  __shared__ bf16 Qs[64 * LQ];
  __shared__ bf16 Ks[64 * LQ];
  __shared__ bf16 Vt[64 * LQ];       // [d][s] transposed V tile
  __shared__ bf16 Ps[4][16 * LQ];    // per-wave P round-trip
  __shared__ float gq[64];
  __shared__ float pbs[128];

  const int t0   = blockIdx.x * 64;
  const int h    = blockIdx.y;
  const int b    = blockIdx.z;
  const int tid  = threadIdx.x;
  const int lane = tid & 63;
  const int wave = tid >> 6;
  const int qd = lane >> 4;
  const int lm = lane & 15;

  const size_t rowbase = (size_t)b * T_SEQ * E_DIM + (size_t)h * D_DIM;

  {
    int r = tid >> 3;            // 0..31
    int c = (tid & 7) * 8;
    *(bf16x8*)&Qs[r * LQ + c]        = *(const bf16x8*)&Qb[rowbase + (size_t)(t0 + r) * E_DIM + c];
    *(bf16x8*)&Qs[(r + 32) * LQ + c] = *(const bf16x8*)&Qb[rowbase + (size_t)(t0 + r + 32) * E_DIM + c];
  }
  if (tid < 64) gq[tid] = gate[((size_t)(b * H_NUM + h)) * T_SEQ + t0 + tid];
  __syncthreads();

  bf16x8 qf0 = *(const bf16x8*)&Qs[(wave * 16 + lm) * LQ + qd * 8];
  bf16x8 qf1 = *(const bf16x8*)&Qs[(wave * 16 + lm) * LQ + 32 + qd * 8];
  float g4[4];
#pragma unroll
  for (int r = 0; r < 4; r++) g4[r] = gq[wave * 16 + qd * 4 + r];

  f32x4 o[4] = {};
  float mi[4], li[4];
#pragma unroll
  for (int r = 0; r < 4; r++) { mi[r] = -INFINITY; li[r] = 0.0f; }

  for (int s0 = 0; s0 < T_SEQ; s0 += 64) {
    __syncthreads();   // previous iter's LDS reads complete before restaging
    {
      int r = tid >> 3;
      int c = (tid & 7) * 8;
      *(bf16x8*)&Ks[r * LQ + c]        = *(const bf16x8*)&Kb[rowbase + (size_t)(s0 + r) * E_DIM + c];
      *(bf16x8*)&Ks[(r + 32) * LQ + c] = *(const bf16x8*)&Kb[rowbase + (size_t)(s0 + r + 32) * E_DIM + c];
      bf16x8 v0 = *(const bf16x8*)&Vb[rowbase + (size_t)(s0 + r) * E_DIM + c];
      bf16x8 v1 = *(const bf16x8*)&Vb[rowbase + (size_t)(s0 + r + 32) * E_DIM + c];
#pragma unroll
      for (int j = 0; j < 8; j++) {
        Vt[(c + j) * LQ + r]      = v0[j];
        Vt[(c + j) * LQ + r + 32] = v1[j];
      }
    }
    if (tid < 127) pbs[tid] = pbt[h * NDELTA + (s0 - t0 + 1984 + tid)];
    __syncthreads();

    // S = Q K^T : 16x64 per wave (C-layout: col=lm, row=qd*4+r)
    f32x4 sc[4];
#pragma unroll
    for (int in = 0; in < 4; in++) {
      bf16x8 kf0 = *(const bf16x8*)&Ks[(in * 16 + lm) * LQ + qd * 8];
      bf16x8 kf1 = *(const bf16x8*)&Ks[(in * 16 + lm) * LQ + 32 + qd * 8];
      f32x4 t = {};
      t = __builtin_amdgcn_mfma_f32_16x16x32_bf16(qf0, kf0, t, 0, 0, 0);
      t = __builtin_amdgcn_mfma_f32_16x16x32_bf16(qf1, kf1, t, 0, 0, 0);
      sc[in] = t;
    }
    // gated position bias: delta = (s0+scol) - (t0+qrow); pbs idx = scol - qrow + 63
#pragma unroll
    for (int in = 0; in < 4; in++) {
      int scol = in * 16 + lm;
#pragma unroll
      for (int r = 0; r < 4; r++) {
        int qrow = wave * 16 + qd * 4 + r;
        sc[in][r] += g4[r] * pbs[scol - qrow + 63];
      }
    }
    // online softmax per row (16 lanes of a quad share rows qd*4+r)
#pragma unroll
    for (int r = 0; r < 4; r++) {
      float mloc = fmaxf(fmaxf(sc[0][r], sc[1][r]), fmaxf(sc[2][r], sc[3][r]));
      mloc = fmaxf(mloc, __shfl_xor(mloc, 1));
      mloc = fmaxf(mloc, __shfl_xor(mloc, 2));
      mloc = fmaxf(mloc, __shfl_xor(mloc, 4));
      mloc = fmaxf(mloc, __shfl_xor(mloc, 8));
      float mnew = fmaxf(mi[r], mloc);
      float alpha_r = __expf(mi[r] - mnew);
      mi[r] = mnew;
      float rsum = 0.0f;
#pragma unroll
      for (int in = 0; in < 4; in++) {
        float pv = __expf(sc[in][r] - mnew);
        sc[in][r] = pv;
        rsum += pv;
      }
      rsum += __shfl_xor(rsum, 1);
      rsum += __shfl_xor(rsum, 2);
      rsum += __shfl_xor(rsum, 4);
      rsum += __shfl_xor(rsum, 8);
      li[r] = li[r] * alpha_r + rsum;
#pragma unroll
      for (int in = 0; in < 4; in++) o[in][r] *= alpha_r;
    }
    // P -> LDS (C-layout write), read back as A-fragments
#pragma unroll
    for (int in = 0; in < 4; in++)
#pragma unroll
      for (int r = 0; r < 4; r++)
        Ps[wave][(qd * 4 + r) * LQ + in * 16 + lm] = (bf16)sc[in][r];
    __syncthreads();
    bf16x8 pf0 = *(const bf16x8*)&Ps[wave][lm * LQ + qd * 8];
    bf16x8 pf1 = *(const bf16x8*)&Ps[wave][lm * LQ + 32 + qd * 8];
#pragma unroll
    for (int in = 0; in < 4; in++) {
      bf16x8 vf0 = *(const bf16x8*)&Vt[(in * 16 + lm) * LQ + qd * 8];
      bf16x8 vf1 = *(const bf16x8*)&Vt[(in * 16 + lm) * LQ + 32 + qd * 8];
      o[in] = __builtin_amdgcn_mfma_f32_16x16x32_bf16(pf0, vf0, o[in], 0, 0, 0);
      o[in] = __builtin_amdgcn_mfma_f32_16x16x32_bf16(pf1, vf1, o[in], 0, 0, 0);
    }
  }

#pragma unroll
  for (int in = 0; in < 4; in++) {
#pragma unroll
    for (int r = 0; r < 4; r++) {
      int t = t0 + wave * 16 + qd * 4 + r;
      float val = o[in][r] / li[r];
      ctx[(size_t)(b * T_SEQ + t) * E_DIM + h * D_DIM + in * 16 + lm] = (bf16)val;
    }
  }
}

// ---------------- orchestration ----------------
extern "C" void kernel_launch(void* const* d_in, const int* in_sizes, int n_in,
                              void* d_out, int out_size, void* d_ws, size_t ws_size,
                              hipStream_t stream)
{
  const float* hs     = (const float*)d_in[0];
  const float* q_w    = (const float*)d_in[1];
  const float* q_b    = (const float*)d_in[2];
  const float* k_w    = (const float*)d_in[3];
  const float* k_b    = (const float*)d_in[4];
  const float* v_w    = (const float*)d_in[5];
  const float* v_b    = (const float*)d_in[6];
  const float* out_w  = (const float*)d_in[7];
  const float* out_b  = (const float*)d_in[8];
  const float* rel    = (const float*)d_in[9];
  const float* gconst = (const float*)d_in[10];
  const float* gru_w  = (const float*)d_in[11];
  const float* gru_b  = (const float*)d_in[12];

  char* p = (char*)d_ws;
  bf16* hsb  = (bf16*)p; p += (size_t)4096 * 1024 * 2;
  bf16* wqb  = (bf16*)p; p += (size_t)1024 * 1024 * 2;
  bf16* wkb  = (bf16*)p; p += (size_t)1024 * 1024 * 2;
  bf16* wvb  = (bf16*)p; p += (size_t)1024 * 1024 * 2;
  bf16* wob  = (bf16*)p; p += (size_t)1024 * 1024 * 2;
  bf16* Qb   = (bf16*)p; p += (size_t)4096 * 1024 * 2;
  bf16* Kb   = (bf16*)p; p += (size_t)4096 * 1024 * 2;
  bf16* Vb   = (bf16*)p; p += (size_t)4096 * 1024 * 2;
  bf16* ctxb = (bf16*)p; p += (size_t)4096 * 1024 * 2;
  float* gatep = (float*)p; p += (size_t)2 * H_NUM * T_SEQ * 4;
  float* pbt   = (float*)p; p += (size_t)H_NUM * NDELTA * 4;

  // hs: 4096*1024 floats = 1,048,576 float4 groups -> 4096 blocks of 256
  cast_bf16_kernel<<<4096, 256, 0, stream>>>(hs, hsb, 1048576);
  // weights: 1024*1024 floats = 262,144 float4 groups -> 1024 blocks of 256
  cast_bf16_kernel<<<1024, 256, 0, stream>>>(q_w,   wqb, 262144);
  cast_bf16_kernel<<<1024, 256, 0, stream>>>(k_w,   wkb, 262144);
  cast_bf16_kernel<<<1024, 256, 0, stream>>>(v_w,   wvb, 262144);
  cast_bf16_kernel<<<1024, 256, 0, stream>>>(out_w, wob, 262144);
  pb_kernel<<<64, 64, 0, stream>>>(rel, pbt);
  gate_kernel<<<256, 256, 0, stream>>>(hs, gru_w, gru_b, gconst, gatep);

  dim3 gg(8, 32);
  gemm_bt_kernel<true ><<<gg, 256, 0, stream>>>(hsb, wqb, q_b, 0.125f, Qb, 4096, 1024, 1024);
  gemm_bt_kernel<true ><<<gg, 256, 0, stream>>>(hsb, wkb, k_b, 1.0f,   Kb, 4096, 1024, 1024);
  gemm_bt_kernel<true ><<<gg, 256, 0, stream>>>(hsb, wvb, v_b, 1.0f,   Vb, 4096, 1024, 1024);

  attn_kernel<<<dim3(T_SEQ / 64, H_NUM, 2), 256, 0, stream>>>(Qb, Kb, Vb, gatep, pbt, ctxb);

  gemm_bt_kernel<false><<<gg, 256, 0, stream>>>(ctxb, wob, out_b, 1.0f, (float*)d_out, 4096, 1024, 1024);
}